// Round 1
// baseline (1914.418 us; speedup 1.0000x reference)
//
#include <hip/hip_runtime.h>

#define L 4096
#define HH 64
#define CC 128
#define BB 2
#define KD 1152   // C*9

typedef _Float16 f16;
typedef _Float16 f16x8 __attribute__((ext_vector_type(8)));
typedef float f32x4 __attribute__((ext_vector_type(4)));

__device__ __forceinline__ void gl_lds16(const f16* g, f16* l) {
  __builtin_amdgcn_global_load_lds(
      (const __attribute__((address_space(1))) void*)g,
      (__attribute__((address_space(3))) void*)l, 16, 0, 0);
}

// sigma: involution converting row-major flat <-> col-major flat (64x64)
__device__ __forceinline__ int sigma_(int j) { return ((j & 63) << 6) | (j >> 6); }

// fused score with exact reference wrap semantics (conv on flat LxL, twice, with transpose)
__device__ __forceinline__ float fused_val(const float* __restrict__ Sb, int cK, int cQ) {
  float acc = 0.f;
#pragma unroll
  for (int s = -1; s <= 1; ++s) {
    int a = cK + s, bq = cQ + s;
    if ((unsigned)a < L && (unsigned)bq < L) {
      int jk = sigma_(a), jq = sigma_(bq);
#pragma unroll
      for (int t = -1; t <= 1; ++t) {
        int p = jk + t, r = jq + t;
        if ((unsigned)p < L && (unsigned)r < L) acc += Sb[(size_t)p * L + r];
      }
    }
  }
  return acc;
}

// ---------------- kernel 1a: im2col of f (FP) and normalized b (WN), f16 ----------------
__global__ __launch_bounds__(256) void k_prep_patches(
    const float* __restrict__ f, const float* __restrict__ b,
    f16* __restrict__ WN, f16* __restrict__ FP) {
  int wid = threadIdx.x >> 6;
  int lane = threadIdx.x & 63;
  int loc = blockIdx.x * 4 + wid;          // 0..8191 = batch*L + k
  int batch = loc >> 12;
  int k = loc & (L - 1);
  int ky = k >> 6, kx = k & 63;
  const float* bp = b + (size_t)batch * CC * L;
  const float* fp_ = f + (size_t)batch * CC * L;
  float bv[18], fv[18];
  float ss = 0.f;
#pragma unroll
  for (int it = 0; it < 18; ++it) {
    int d = it * 64 + lane;
    int c = d / 9;
    int r = d - c * 9;
    int yy = ky + (r / 3) - 1, xx = kx + (r % 3) - 1;
    bool ok = (yy >= 0 && yy < 64 && xx >= 0 && xx < 64);
    float vb = ok ? bp[(size_t)c * L + yy * 64 + xx] : 0.f;
    float vf = ok ? fp_[(size_t)c * L + yy * 64 + xx] : 0.f;
    bv[it] = vb; fv[it] = vf;
    ss += vb * vb;
  }
#pragma unroll
  for (int m = 32; m >= 1; m >>= 1) ss += __shfl_xor(ss, m, 64);
  float scale = 1.f / fmaxf(sqrtf(ss), 1e-4f);
  f16* wn = WN + (size_t)loc * KD;
  f16* fpo = FP + (size_t)loc * KD;
#pragma unroll
  for (int it = 0; it < 18; ++it) {
    int d = it * 64 + lane;
    wn[d] = (f16)(bv[it] * scale);
    fpo[d] = (f16)(fv[it]);
  }
}

// ---------------- kernel 1b: shifted+masked f16 copies of b for the 4 aggregation taps ---
// bm[tap][batch][c][k] = (ky+di<64 && kx+dj<64) ? b[batch][c][k + di*64 + dj] : 0
// with tap = i*2+j (attn shift i*64+j), di=1-i, dj=1-j.
__global__ void k_prep_bm(const float* __restrict__ b, f16* __restrict__ bm) {
  int idx = blockIdx.x * 256 + threadIdx.x;  // total 4*2*128*4096
  int k = idx & (L - 1);
  int c = (idx >> 12) & (CC - 1);
  int bt = idx >> 19;           // tap*2 + batch
  int batch = bt & 1;
  int tap = bt >> 1;
  int di = 1 - (tap >> 1), dj = 1 - (tap & 1);
  int ky = k >> 6, kx = k & 63;
  float v = 0.f;
  if (ky + di < 64 && kx + dj < 64)
    v = b[((size_t)batch * CC + c) * L + k + di * 64 + dj];
  bm[idx] = (f16)v;
}

// ---------------- kernel 1c: mask validity mm[k] -----------------------------------------
__global__ void k_prep_mm(const float* __restrict__ mask, float* __restrict__ mmv) {
  int k = blockIdx.x * 256 + threadIdx.x;
  if (k >= L) return;
  int ky = k >> 6, kx = k & 63;
  float s = 0.f;
  for (int i = 0; i < 3; ++i)
    for (int j = 0; j < 3; ++j) {
      int yy = ky + i - 1, xx = kx + j - 1;
      if (yy >= 0 && yy < 64 && xx >= 0 && xx < 64) s += mask[yy * 64 + xx];
    }
  mmv[k] = (s == 0.f) ? 1.f : 0.f;
}

// ---------------- kernel 2: scores GEMM  S[k,q] = sum_d WN[k,d]*FP[q,d] ------------------
// 128x128 tile, BK=32, 4 waves (2x2), f16 MFMA 16x16x32, global_load_lds staging.
__global__ __launch_bounds__(256) void k_gemm_scores(
    const f16* __restrict__ WN, const f16* __restrict__ FP, float* __restrict__ S) {
  __shared__ f16 As[128 * 32];
  __shared__ f16 Bs[128 * 32];
  int qt = blockIdx.x, kt = blockIdx.y, batch = blockIdx.z;
  int tid = threadIdx.x, wid = tid >> 6, lane = tid & 63;
  int wr = wid >> 1, wc = wid & 1;
  const f16* Abase = WN + ((size_t)batch * L + kt * 128) * KD;
  const f16* Bbase = FP + ((size_t)batch * L + qt * 128) * KD;
  f32x4 acc[4][4] = {};
  int srow = lane >> 2;          // 0..15
  int scol = (lane & 3) * 8;     // f16 offset within 32
  for (int kk = 0; kk < KD; kk += 32) {
    __syncthreads();
    {
      int r0 = wid * 32 + srow;
      gl_lds16(Abase + (size_t)r0 * KD + kk + scol, As + r0 * 32 + scol);
      gl_lds16(Abase + (size_t)(r0 + 16) * KD + kk + scol, As + (r0 + 16) * 32 + scol);
      gl_lds16(Bbase + (size_t)r0 * KD + kk + scol, Bs + r0 * 32 + scol);
      gl_lds16(Bbase + (size_t)(r0 + 16) * KD + kk + scol, Bs + (r0 + 16) * 32 + scol);
    }
    __syncthreads();
    f16x8 af[4], bf[4];
    int kb = (lane >> 4) * 8;
    int rA = wr * 64 + (lane & 15);
    int rB = wc * 64 + (lane & 15);
#pragma unroll
    for (int m = 0; m < 4; ++m) af[m] = *(const f16x8*)(As + (rA + m * 16) * 32 + kb);
#pragma unroll
    for (int n = 0; n < 4; ++n) bf[n] = *(const f16x8*)(Bs + (rB + n * 16) * 32 + kb);
#pragma unroll
    for (int m = 0; m < 4; ++m)
#pragma unroll
      for (int n = 0; n < 4; ++n)
        acc[m][n] = __builtin_amdgcn_mfma_f32_16x16x32_f16(af[m], bf[n], acc[m][n], 0, 0, 0);
  }
  float* Srow = S + (size_t)batch * L * L;
  int kbase = kt * 128 + wr * 64 + (lane >> 4) * 4;
  int qbase = qt * 128 + wc * 64 + (lane & 15);
#pragma unroll
  for (int m = 0; m < 4; ++m)
#pragma unroll
    for (int r = 0; r < 4; ++r) {
      float* dst = Srow + (size_t)(kbase + m * 16 + r) * L + qbase;
#pragma unroll
      for (int n = 0; n < 4; ++n) dst[n * 16] = acc[m][n][r];
    }
}

// ---------------- kernel 3: fuse + online softmax partial stats --------------------------
__global__ __launch_bounds__(256) void k_softmax_stats(
    const float* __restrict__ S, const float* __restrict__ mmv,
    float* __restrict__ pm, float* __restrict__ pl) {
  int q = blockIdx.x * 256 + threadIdx.x;
  int kc = blockIdx.y, batch = blockIdx.z;
  const float* Sb = S + (size_t)batch * L * L;
  int cQ = sigma_(q);
  float m = -3.0e38f, l = 0.f;
  int kend = kc * 512 + 512;
  for (int k = kc * 512; k < kend; ++k) {
    float logit = 0.f;
    if (mmv[k] != 0.f) logit = 10.f * fused_val(Sb, sigma_(k), cQ);
    float nm = fmaxf(m, logit);
    l = l * __expf(m - nm) + __expf(logit - nm);
    m = nm;
  }
  int qi = batch * L + q;
  pm[qi * 8 + kc] = m;
  pl[qi * 8 + kc] = l;
}

// ---------------- kernel 3b: combine partials -------------------------------------------
__global__ void k_softmax_reduce(const float* __restrict__ pm, const float* __restrict__ pl,
                                 float* __restrict__ Mq, float* __restrict__ Lq) {
  int qi = blockIdx.x * 256 + threadIdx.x;
  if (qi >= BB * L) return;
  float M = -3.0e38f;
#pragma unroll
  for (int i = 0; i < 8; ++i) M = fmaxf(M, pm[qi * 8 + i]);
  float Ls = 0.f;
#pragma unroll
  for (int i = 0; i < 8; ++i) Ls += pl[qi * 8 + i] * __expf(pm[qi * 8 + i] - M);
  Mq[qi] = M;
  Lq[qi] = Ls;
}

// ---------------- kernel 4: write attn (f16, [b][k][q]) ---------------------------------
__global__ __launch_bounds__(256) void k_attn(
    const float* __restrict__ S, const float* __restrict__ mmv,
    const float* __restrict__ Mq, const float* __restrict__ Lq,
    f16* __restrict__ attn) {
  int q = blockIdx.x * 256 + threadIdx.x;
  int kc = blockIdx.y, batch = blockIdx.z;
  const float* Sb = S + (size_t)batch * L * L;
  f16* An = attn + (size_t)batch * L * L;
  int qi = batch * L + q;
  float M = Mq[qi];
  float inv = 1.f / Lq[qi];
  int cQ = sigma_(q);
  int kend = kc * 512 + 512;
  for (int k = kc * 512; k < kend; ++k) {
    float v = 0.f;
    if (mmv[k] != 0.f)
      v = __expf(10.f * fused_val(Sb, sigma_(k), cQ) - M) * inv;
    An[(size_t)k * L + q] = (f16)v;
  }
}

// ---------------- kernel 5: aggregation, Y[c,p] = 1/4 sum_taps sum_k A_tap[c,k]*attn[k,p+d]
// BM=128 (all c), BN=32, BK=32, 4 waves stacked on M, f16 MFMA.
__global__ __launch_bounds__(256) void k_agg(
    const f16* __restrict__ attn, const f16* __restrict__ bm, float* __restrict__ out) {
  __shared__ f16 Asm[4 * 128 * 32];   // [tap][c][kk] linear
  __shared__ f16 Bt[104 * 40];        // [pp][kk], row stride 40 f16 (bank-friendly)
  int pt = blockIdx.x, batch = blockIdx.y;
  int p0 = pt * 32;
  int tid = threadIdx.x, wid = tid >> 6, lane = tid & 63;
  const f16* attnB = attn + (size_t)batch * L * L;
  f32x4 acc[2][2] = {};
  for (int k0 = 0; k0 < L; k0 += 32) {
    __syncthreads();
    // stage A from bm (linear, 8 gload_lds per wave)
#pragma unroll
    for (int i = 0; i < 8; ++i) {
      int R = wid * 128 + i * 16 + (lane >> 2);   // (tap*128 + c)
      int tap = R >> 7, c = R & 127;
      const f16* g = bm + (((size_t)(tap * 2 + batch) * CC + c) * L) + k0 + (lane & 3) * 8;
      gl_lds16(g, Asm + R * 32 + (lane & 3) * 8);
    }
    // stage B transposed: Bt[pp][kk] = attn[k0+kk][p0+pp], pp in [0,104)
#pragma unroll
    for (int it = 0; it < 2; ++it) {
      int tau = it * 256 + tid;
      if (tau < 416) {
        int kk2 = tau / 13, ch = tau - kk2 * 13;
        int pbase = p0 + ch * 8;
        f16 v[8];
        if (pbase + 7 < L) {
          f16x8 vv = *(const f16x8*)(attnB + (size_t)(k0 + kk2) * L + pbase);
#pragma unroll
          for (int e = 0; e < 8; ++e) v[e] = vv[e];
        } else {
#pragma unroll
          for (int e = 0; e < 8; ++e)
            v[e] = (pbase + e < L) ? attnB[(size_t)(k0 + kk2) * L + pbase + e] : (f16)0.f;
        }
#pragma unroll
        for (int e = 0; e < 8; ++e) Bt[(ch * 8 + e) * 40 + kk2] = v[e];
      }
    }
    __syncthreads();
    int kb = (lane >> 4) * 8;
#pragma unroll
    for (int tap = 0; tap < 4; ++tap) {
      int dlt = (tap >> 1) * 64 + (tap & 1);
      f16x8 af[2], bf[2];
#pragma unroll
      for (int m = 0; m < 2; ++m)
        af[m] = *(const f16x8*)(Asm + (tap * 128 + wid * 32 + m * 16 + (lane & 15)) * 32 + kb);
#pragma unroll
      for (int n = 0; n < 2; ++n)
        bf[n] = *(const f16x8*)(Bt + (n * 16 + (lane & 15) + dlt) * 40 + kb);
#pragma unroll
      for (int m = 0; m < 2; ++m)
#pragma unroll
        for (int n = 0; n < 2; ++n)
          acc[m][n] = __builtin_amdgcn_mfma_f32_16x16x32_f16(af[m], bf[n], acc[m][n], 0, 0, 0);
    }
  }
  int cb = wid * 32 + (lane >> 4) * 4;
  int pb = p0 + (lane & 15);
#pragma unroll
  for (int m = 0; m < 2; ++m)
#pragma unroll
    for (int n = 0; n < 2; ++n)
#pragma unroll
      for (int r = 0; r < 4; ++r) {
        int c = cb + m * 16 + r;
        int p = pb + n * 16;
        int u = p >> 6, v = p & 63;
        float val = (u < 63 && v < 63) ? acc[m][n][r] * 0.25f : 0.f;
        out[((size_t)batch * CC + c) * L + p] = val;
      }
}

extern "C" void kernel_launch(void* const* d_in, const int* in_sizes, int n_in,
                              void* d_out, int out_size, void* d_ws, size_t ws_size,
                              hipStream_t stream) {
  const float* f = (const float*)d_in[0];
  const float* b = (const float*)d_in[1];
  const float* mask = (const float*)d_in[2];
  float* out = (float*)d_out;
  char* ws = (char*)d_ws;

  f16* WN    = (f16*)(ws + 0);            // 18,874,368 B
  f16* FP    = (f16*)(ws + 18874368);     // 18,874,368 B
  float* S   = (float*)(ws + 37748736);   // 134,217,728 B
  f16* attn  = (f16*)(ws + 171966464);    // 67,108,864 B
  f16* bm    = (f16*)(ws + 239075328);    // 8,388,608 B
  float* mmv = (float*)(ws + 247463936);  // 16,384 B
  float* pm  = (float*)(ws + 247480320);  // 262,144 B
  float* pl  = (float*)(ws + 247742464);  // 262,144 B
  float* Mq  = (float*)(ws + 248004608);  // 32,768 B
  float* Lq  = (float*)(ws + 248037376);  // 32,768 B

  k_prep_patches<<<dim3(2048), dim3(256), 0, stream>>>(f, b, WN, FP);
  k_prep_bm<<<dim3(16384), dim3(256), 0, stream>>>(b, bm);
  k_prep_mm<<<dim3(16), dim3(256), 0, stream>>>(mask, mmv);
  k_gemm_scores<<<dim3(32, 32, 2), dim3(256), 0, stream>>>(WN, FP, S);
  k_softmax_stats<<<dim3(16, 8, 2), dim3(256), 0, stream>>>(S, mmv, pm, pl);
  k_softmax_reduce<<<dim3(32), dim3(256), 0, stream>>>(pm, pl, Mq, Lq);
  k_attn<<<dim3(16, 8, 2), dim3(256), 0, stream>>>(S, mmv, Mq, Lq, attn);
  k_agg<<<dim3(128, 2), dim3(256), 0, stream>>>(attn, bm, out);
}

// Round 2
// 884.814 us; speedup vs baseline: 2.1636x; 2.1636x over previous
//
#include <hip/hip_runtime.h>

#define L 4096
#define HH 64
#define CC 128
#define BB 2
#define KD 1152   // C*9

typedef _Float16 f16;
typedef _Float16 f16x8 __attribute__((ext_vector_type(8)));
typedef float f32x4 __attribute__((ext_vector_type(4)));

__device__ __forceinline__ void gl_lds16(const f16* g, f16* l) {
  __builtin_amdgcn_global_load_lds(
      (const __attribute__((address_space(1))) void*)g,
      (__attribute__((address_space(3))) void*)l, 16, 0, 0);
}

// sigma: involution converting row-major flat <-> col-major flat (64x64)
__device__ __forceinline__ int sigma_(int j) { return ((j & 63) << 6) | (j >> 6); }

// ---------------- kernel 1a: im2col of f (FP) and normalized b (WN), f16 ----------------
__global__ __launch_bounds__(256) void k_prep_patches(
    const float* __restrict__ f, const float* __restrict__ b,
    f16* __restrict__ WN, f16* __restrict__ FP) {
  int wid = threadIdx.x >> 6;
  int lane = threadIdx.x & 63;
  int loc = blockIdx.x * 4 + wid;          // 0..8191 = batch*L + k
  int batch = loc >> 12;
  int k = loc & (L - 1);
  int ky = k >> 6, kx = k & 63;
  const float* bp = b + (size_t)batch * CC * L;
  const float* fp_ = f + (size_t)batch * CC * L;
  float bv[18], fv[18];
  float ss = 0.f;
#pragma unroll
  for (int it = 0; it < 18; ++it) {
    int d = it * 64 + lane;
    int c = d / 9;
    int r = d - c * 9;
    int yy = ky + (r / 3) - 1, xx = kx + (r % 3) - 1;
    bool ok = (yy >= 0 && yy < 64 && xx >= 0 && xx < 64);
    float vb = ok ? bp[(size_t)c * L + yy * 64 + xx] : 0.f;
    float vf = ok ? fp_[(size_t)c * L + yy * 64 + xx] : 0.f;
    bv[it] = vb; fv[it] = vf;
    ss += vb * vb;
  }
#pragma unroll
  for (int m = 32; m >= 1; m >>= 1) ss += __shfl_xor(ss, m, 64);
  float scale = 1.f / fmaxf(sqrtf(ss), 1e-4f);
  f16* wn = WN + (size_t)loc * KD;
  f16* fpo = FP + (size_t)loc * KD;
#pragma unroll
  for (int it = 0; it < 18; ++it) {
    int d = it * 64 + lane;
    wn[d] = (f16)(bv[it] * scale);
    fpo[d] = (f16)(fv[it]);
  }
}

// ---------------- kernel 1b: shifted+masked f16 copies of b for the 4 aggregation taps ---
__global__ void k_prep_bm(const float* __restrict__ b, f16* __restrict__ bm) {
  int idx = blockIdx.x * 256 + threadIdx.x;  // total 4*2*128*4096
  int k = idx & (L - 1);
  int c = (idx >> 12) & (CC - 1);
  int bt = idx >> 19;           // tap*2 + batch
  int batch = bt & 1;
  int tap = bt >> 1;
  int di = 1 - (tap >> 1), dj = 1 - (tap & 1);
  int ky = k >> 6, kx = k & 63;
  float v = 0.f;
  if (ky + di < 64 && kx + dj < 64)
    v = b[((size_t)batch * CC + c) * L + k + di * 64 + dj];
  bm[idx] = (f16)v;
}

// ---------------- kernel 1c: mask validity mm[k] -----------------------------------------
__global__ void k_prep_mm(const float* __restrict__ mask, float* __restrict__ mmv) {
  int k = blockIdx.x * 256 + threadIdx.x;
  if (k >= L) return;
  int ky = k >> 6, kx = k & 63;
  float s = 0.f;
  for (int i = 0; i < 3; ++i)
    for (int j = 0; j < 3; ++j) {
      int yy = ky + i - 1, xx = kx + j - 1;
      if (yy >= 0 && yy < 64 && xx >= 0 && xx < 64) s += mask[yy * 64 + xx];
    }
  mmv[k] = (s == 0.f) ? 1.f : 0.f;
}

// ---------------- kernel 2: scores GEMM  S[k,q] = sum_d WN[k,d]*FP[q,d], f16 out ---------
__global__ __launch_bounds__(256) void k_gemm_scores(
    const f16* __restrict__ WN, const f16* __restrict__ FP, f16* __restrict__ S) {
  __shared__ f16 As[128 * 32];
  __shared__ f16 Bs[128 * 32];
  int qt = blockIdx.x, kt = blockIdx.y, batch = blockIdx.z;
  int tid = threadIdx.x, wid = tid >> 6, lane = tid & 63;
  int wr = wid >> 1, wc = wid & 1;
  const f16* Abase = WN + ((size_t)batch * L + kt * 128) * KD;
  const f16* Bbase = FP + ((size_t)batch * L + qt * 128) * KD;
  f32x4 acc[4][4] = {};
  int srow = lane >> 2;          // 0..15
  int scol = (lane & 3) * 8;     // f16 offset within 32
  for (int kk = 0; kk < KD; kk += 32) {
    __syncthreads();
    {
      int r0 = wid * 32 + srow;
      gl_lds16(Abase + (size_t)r0 * KD + kk + scol, As + r0 * 32 + scol);
      gl_lds16(Abase + (size_t)(r0 + 16) * KD + kk + scol, As + (r0 + 16) * 32 + scol);
      gl_lds16(Bbase + (size_t)r0 * KD + kk + scol, Bs + r0 * 32 + scol);
      gl_lds16(Bbase + (size_t)(r0 + 16) * KD + kk + scol, Bs + (r0 + 16) * 32 + scol);
    }
    __syncthreads();
    f16x8 af[4], bf[4];
    int kb = (lane >> 4) * 8;
    int rA = wr * 64 + (lane & 15);
    int rB = wc * 64 + (lane & 15);
#pragma unroll
    for (int m = 0; m < 4; ++m) af[m] = *(const f16x8*)(As + (rA + m * 16) * 32 + kb);
#pragma unroll
    for (int n = 0; n < 4; ++n) bf[n] = *(const f16x8*)(Bs + (rB + n * 16) * 32 + kb);
#pragma unroll
    for (int m = 0; m < 4; ++m)
#pragma unroll
      for (int n = 0; n < 4; ++n)
        acc[m][n] = __builtin_amdgcn_mfma_f32_16x16x32_f16(af[m], bf[n], acc[m][n], 0, 0, 0);
  }
  f16* Srow = S + (size_t)batch * L * L;
  int kbase = kt * 128 + wr * 64 + (lane >> 4) * 4;
  int qbase = qt * 128 + wc * 64 + (lane & 15);
#pragma unroll
  for (int m = 0; m < 4; ++m)
#pragma unroll
    for (int r = 0; r < 4; ++r) {
      f16* dst = Srow + (size_t)(kbase + m * 16 + r) * L + qbase;
#pragma unroll
      for (int n = 0; n < 4; ++n) dst[n * 16] = (f16)acc[m][n][r];
    }
}

// ---------------- kernel 2b: diagonal 3-tap conv in flat space (coalesced) ---------------
// T1[i][j] = sum_{t=-1..1, 0<=i+t<L, 0<=j+t<L} S[i+t][j+t]
__global__ __launch_bounds__(256) void k_fuse1(
    const f16* __restrict__ S, float* __restrict__ T1) {
  int idx = blockIdx.x * 256 + threadIdx.x;   // 2*4096*512 threads
  int j0 = (idx & 511) * 8;
  int i = (idx >> 9) & (L - 1);
  int batch = idx >> 21;
  const f16* Sb = S + (size_t)batch * L * L;
  float acc[8] = {0.f, 0.f, 0.f, 0.f, 0.f, 0.f, 0.f, 0.f};
  // t = -1
  if (i - 1 >= 0) {
    const f16* r = Sb + (size_t)(i - 1) * L + j0;
    f16x8 v = *(const f16x8*)r;
    acc[0] += (j0 > 0) ? (float)r[-1] : 0.f;
#pragma unroll
    for (int e = 1; e < 8; ++e) acc[e] += (float)v[e - 1];
  }
  // t = 0
  {
    const f16* r = Sb + (size_t)i * L + j0;
    f16x8 v = *(const f16x8*)r;
#pragma unroll
    for (int e = 0; e < 8; ++e) acc[e] += (float)v[e];
  }
  // t = +1
  if (i + 1 < L) {
    const f16* r = Sb + (size_t)(i + 1) * L + j0;
    f16x8 v = *(const f16x8*)r;
#pragma unroll
    for (int e = 0; e < 7; ++e) acc[e] += (float)v[e + 1];
    acc[7] += (j0 + 8 < L) ? (float)r[8] : 0.f;
  }
  float* dst = T1 + (size_t)batch * L * L + (size_t)i * L + j0;
  *(f32x4*)dst = *(f32x4*)&acc[0];
  *(f32x4*)(dst + 4) = *(f32x4*)&acc[4];
}

// ---------------- kernel 3: permuted 3-tap + online softmax partial stats ----------------
__global__ __launch_bounds__(256) void k_softmax_stats(
    const float* __restrict__ T1, const float* __restrict__ mmv,
    float* __restrict__ pm, float* __restrict__ pl) {
  int q = blockIdx.x * 256 + threadIdx.x;
  int kc = blockIdx.y, batch = blockIdx.z;
  const float* Tb = T1 + (size_t)batch * L * L;
  int cQ = sigma_(q);
  int colv[3]; float colok[3];
#pragma unroll
  for (int s = 0; s < 3; ++s) {
    int bq = cQ + s - 1;
    bool ok = (unsigned)bq < L;
    colok[s] = ok ? 1.f : 0.f;
    colv[s] = ok ? sigma_(bq) : 0;
  }
  float m = -3.0e38f, l = 0.f;
  int kend = kc * 256 + 256;
  for (int k = kc * 256; k < kend; ++k) {
    int cK = sigma_(k);
    float acc = 0.f;
#pragma unroll
    for (int s = 0; s < 3; ++s) {
      int a = cK + s - 1;
      if ((unsigned)a < L) {
        int row = sigma_(a);
        acc += colok[s] * Tb[(size_t)row * L + colv[s]];
      }
    }
    float logit = (mmv[k] != 0.f) ? 10.f * acc : 0.f;
    float nm = fmaxf(m, logit);
    l = l * __expf(m - nm) + __expf(logit - nm);
    m = nm;
  }
  int qi = batch * L + q;
  pm[qi * 16 + kc] = m;
  pl[qi * 16 + kc] = l;
}

// ---------------- kernel 3b: combine partials -------------------------------------------
__global__ void k_softmax_reduce(const float* __restrict__ pm, const float* __restrict__ pl,
                                 float* __restrict__ Mq, float* __restrict__ Lq) {
  int qi = blockIdx.x * 256 + threadIdx.x;
  if (qi >= BB * L) return;
  float M = -3.0e38f;
#pragma unroll
  for (int i = 0; i < 16; ++i) M = fmaxf(M, pm[qi * 16 + i]);
  float Ls = 0.f;
#pragma unroll
  for (int i = 0; i < 16; ++i) Ls += pl[qi * 16 + i] * __expf(pm[qi * 16 + i] - M);
  Mq[qi] = M;
  Lq[qi] = Ls;
}

// ---------------- kernel 4: write attn (f16, [b][k][q]) ---------------------------------
__global__ __launch_bounds__(256) void k_attn(
    const float* __restrict__ T1, const float* __restrict__ mmv,
    const float* __restrict__ Mq, const float* __restrict__ Lq,
    f16* __restrict__ attn) {
  int q = blockIdx.x * 256 + threadIdx.x;
  int kc = blockIdx.y, batch = blockIdx.z;
  const float* Tb = T1 + (size_t)batch * L * L;
  f16* An = attn + (size_t)batch * L * L;
  int qi = batch * L + q;
  float M = Mq[qi];
  float inv = 1.f / Lq[qi];
  int cQ = sigma_(q);
  int colv[3]; float colok[3];
#pragma unroll
  for (int s = 0; s < 3; ++s) {
    int bq = cQ + s - 1;
    bool ok = (unsigned)bq < L;
    colok[s] = ok ? 1.f : 0.f;
    colv[s] = ok ? sigma_(bq) : 0;
  }
  int kend = kc * 256 + 256;
  for (int k = kc * 256; k < kend; ++k) {
    int cK = sigma_(k);
    float acc = 0.f;
#pragma unroll
    for (int s = 0; s < 3; ++s) {
      int a = cK + s - 1;
      if ((unsigned)a < L) {
        int row = sigma_(a);
        acc += colok[s] * Tb[(size_t)row * L + colv[s]];
      }
    }
    float v = 0.f;
    if (mmv[k] != 0.f) v = __expf(10.f * acc - M) * inv;
    An[(size_t)k * L + q] = (f16)v;
  }
}

// ---------------- kernel 5: aggregation -------------------------------------------------
__global__ __launch_bounds__(256) void k_agg(
    const f16* __restrict__ attn, const f16* __restrict__ bm, float* __restrict__ out) {
  __shared__ f16 Asm[4 * 128 * 32];   // [tap][c][kk] linear
  __shared__ f16 Bt[104 * 40];        // [pp][kk], row stride 40 f16
  int pt = blockIdx.x, batch = blockIdx.y;
  int p0 = pt * 32;
  int tid = threadIdx.x, wid = tid >> 6, lane = tid & 63;
  const f16* attnB = attn + (size_t)batch * L * L;
  f32x4 acc[2][2] = {};
  for (int k0 = 0; k0 < L; k0 += 32) {
    __syncthreads();
#pragma unroll
    for (int i = 0; i < 8; ++i) {
      int R = wid * 128 + i * 16 + (lane >> 2);   // (tap*128 + c)
      int tap = R >> 7, c = R & 127;
      const f16* g = bm + (((size_t)(tap * 2 + batch) * CC + c) * L) + k0 + (lane & 3) * 8;
      gl_lds16(g, Asm + R * 32 + (lane & 3) * 8);
    }
#pragma unroll
    for (int it = 0; it < 2; ++it) {
      int tau = it * 256 + tid;
      if (tau < 416) {
        int kk2 = tau / 13, ch = tau - kk2 * 13;
        int pbase = p0 + ch * 8;
        f16 v[8];
        if (pbase + 7 < L) {
          f16x8 vv = *(const f16x8*)(attnB + (size_t)(k0 + kk2) * L + pbase);
#pragma unroll
          for (int e = 0; e < 8; ++e) v[e] = vv[e];
        } else {
#pragma unroll
          for (int e = 0; e < 8; ++e)
            v[e] = (pbase + e < L) ? attnB[(size_t)(k0 + kk2) * L + pbase + e] : (f16)0.f;
        }
#pragma unroll
        for (int e = 0; e < 8; ++e) Bt[(ch * 8 + e) * 40 + kk2] = v[e];
      }
    }
    __syncthreads();
    int kb = (lane >> 4) * 8;
#pragma unroll
    for (int tap = 0; tap < 4; ++tap) {
      int dlt = (tap >> 1) * 64 + (tap & 1);
      f16x8 af[2], bf[2];
#pragma unroll
      for (int m = 0; m < 2; ++m)
        af[m] = *(const f16x8*)(Asm + (tap * 128 + wid * 32 + m * 16 + (lane & 15)) * 32 + kb);
#pragma unroll
      for (int n = 0; n < 2; ++n)
        bf[n] = *(const f16x8*)(Bt + (n * 16 + (lane & 15) + dlt) * 40 + kb);
#pragma unroll
      for (int m = 0; m < 2; ++m)
#pragma unroll
        for (int n = 0; n < 2; ++n)
          acc[m][n] = __builtin_amdgcn_mfma_f32_16x16x32_f16(af[m], bf[n], acc[m][n], 0, 0, 0);
    }
  }
  int cb = wid * 32 + (lane >> 4) * 4;
  int pb = p0 + (lane & 15);
#pragma unroll
  for (int m = 0; m < 2; ++m)
#pragma unroll
    for (int n = 0; n < 2; ++n)
#pragma unroll
      for (int r = 0; r < 4; ++r) {
        int c = cb + m * 16 + r;
        int p = pb + n * 16;
        int u = p >> 6, v = p & 63;
        float val = (u < 63 && v < 63) ? acc[m][n][r] * 0.25f : 0.f;
        out[((size_t)batch * CC + c) * L + p] = val;
      }
}

extern "C" void kernel_launch(void* const* d_in, const int* in_sizes, int n_in,
                              void* d_out, int out_size, void* d_ws, size_t ws_size,
                              hipStream_t stream) {
  const float* f = (const float*)d_in[0];
  const float* b = (const float*)d_in[1];
  const float* mask = (const float*)d_in[2];
  float* out = (float*)d_out;
  char* ws = (char*)d_ws;

  // Lifetimes: S(gemm->fuse1), WN/FP(prep->gemm), T1(fuse1->attn), attn(attn->agg)
  f16* S     = (f16*)(ws + 0);             // 67,108,864 B   [0, 67M)
  f16* attn  = (f16*)(ws + 0);             // aliases S (S dead after fuse1)
  f16* WN    = (f16*)(ws + 67108864);      // 18,874,368 B   (dead after gemm)
  f16* FP    = (f16*)(ws + 85983232);      // 18,874,368 B   (dead after gemm)
  float* T1  = (float*)(ws + 67108864);    // 134,217,728 B  overwrites WN/FP after gemm
  f16* bm    = (f16*)(ws + 201326592);     // 8,388,608 B
  float* mmv = (float*)(ws + 209715200);   // 16,384 B
  float* pm  = (float*)(ws + 209731584);   // 524,288 B
  float* pl  = (float*)(ws + 210255872);   // 524,288 B
  float* Mq  = (float*)(ws + 210780160);   // 32,768 B
  float* Lq  = (float*)(ws + 210812928);   // 32,768 B

  k_prep_patches<<<dim3(2048), dim3(256), 0, stream>>>(f, b, WN, FP);
  k_prep_bm<<<dim3(16384), dim3(256), 0, stream>>>(b, bm);
  k_prep_mm<<<dim3(16), dim3(256), 0, stream>>>(mask, mmv);
  k_gemm_scores<<<dim3(32, 32, 2), dim3(256), 0, stream>>>(WN, FP, S);
  k_fuse1<<<dim3(16384), dim3(256), 0, stream>>>(S, T1);
  k_softmax_stats<<<dim3(16, 16, 2), dim3(256), 0, stream>>>(T1, mmv, pm, pl);
  k_softmax_reduce<<<dim3(32), dim3(256), 0, stream>>>(pm, pl, Mq, Lq);
  k_attn<<<dim3(16, 16, 2), dim3(256), 0, stream>>>(T1, mmv, Mq, Lq, attn);
  k_agg<<<dim3(128, 2), dim3(256), 0, stream>>>(attn, bm, out);
}

// Round 3
// 393.438 us; speedup vs baseline: 4.8659x; 2.2489x over previous
//
#include <hip/hip_runtime.h>

#define L 4096
#define HH 64
#define CC 128
#define BB 2
#define KD 1152   // C*9

typedef _Float16 f16;
typedef _Float16 f16x8 __attribute__((ext_vector_type(8)));
typedef float f32x4 __attribute__((ext_vector_type(4)));

__device__ __forceinline__ void gl_lds16(const f16* g, f16* l) {
  __builtin_amdgcn_global_load_lds(
      (const __attribute__((address_space(1))) void*)g,
      (__attribute__((address_space(3))) void*)l, 16, 0, 0);
}

// sigma: involution converting row-major flat <-> col-major flat (64x64)
__device__ __forceinline__ int sigma_(int j) { return ((j & 63) << 6) | (j >> 6); }

// full 9-tap fused score from S (reference wrap semantics), scalar fallback
__device__ float fuse9(const f16* __restrict__ Sb, int k, int j) {
  float acc = 0.f;
  int cK = sigma_(k), cQ = sigma_(j);
#pragma unroll
  for (int u = -1; u <= 1; ++u) {
    int a = cK + u, bq = cQ + u;
    if ((unsigned)a < L && (unsigned)bq < L) {
      int r = sigma_(a), c = sigma_(bq);
#pragma unroll
      for (int t = -1; t <= 1; ++t) {
        int rr = r + t, cc = c + t;
        if ((unsigned)rr < L && (unsigned)cc < L) acc += (float)Sb[(size_t)rr * L + cc];
      }
    }
  }
  return acc;
}

// ---------------- kernel 1a: im2col of f (FP) and normalized b (WN), f16 ----------------
__global__ __launch_bounds__(256) void k_prep_patches(
    const float* __restrict__ f, const float* __restrict__ b,
    f16* __restrict__ WN, f16* __restrict__ FP) {
  int wid = threadIdx.x >> 6;
  int lane = threadIdx.x & 63;
  int loc = blockIdx.x * 4 + wid;          // 0..8191 = batch*L + k
  int batch = loc >> 12;
  int k = loc & (L - 1);
  int ky = k >> 6, kx = k & 63;
  const float* bp = b + (size_t)batch * CC * L;
  const float* fp_ = f + (size_t)batch * CC * L;
  float bv[18], fv[18];
  float ss = 0.f;
#pragma unroll
  for (int it = 0; it < 18; ++it) {
    int d = it * 64 + lane;
    int c = d / 9;
    int r = d - c * 9;
    int yy = ky + (r / 3) - 1, xx = kx + (r % 3) - 1;
    bool ok = (yy >= 0 && yy < 64 && xx >= 0 && xx < 64);
    float vb = ok ? bp[(size_t)c * L + yy * 64 + xx] : 0.f;
    float vf = ok ? fp_[(size_t)c * L + yy * 64 + xx] : 0.f;
    bv[it] = vb; fv[it] = vf;
    ss += vb * vb;
  }
#pragma unroll
  for (int m = 32; m >= 1; m >>= 1) ss += __shfl_xor(ss, m, 64);
  float scale = 1.f / fmaxf(sqrtf(ss), 1e-4f);
  f16* wn = WN + (size_t)loc * KD;
  f16* fpo = FP + (size_t)loc * KD;
#pragma unroll
  for (int it = 0; it < 18; ++it) {
    int d = it * 64 + lane;
    wn[d] = (f16)(bv[it] * scale);
    fpo[d] = (f16)(fv[it]);
  }
}

// ---------------- kernel 1b: shifted+masked f16 copies of b for the 4 taps ---------------
__global__ void k_prep_bm(const float* __restrict__ b, f16* __restrict__ bm) {
  int idx = blockIdx.x * 256 + threadIdx.x;  // total 4*2*128*4096
  int k = idx & (L - 1);
  int c = (idx >> 12) & (CC - 1);
  int bt = idx >> 19;           // tap*2 + batch
  int batch = bt & 1;
  int tap = bt >> 1;
  int di = 1 - (tap >> 1), dj = 1 - (tap & 1);
  int ky = k >> 6, kx = k & 63;
  float v = 0.f;
  if (ky + di < 64 && kx + dj < 64)
    v = b[((size_t)batch * CC + c) * L + k + di * 64 + dj];
  bm[idx] = (f16)v;
}

// ---------------- kernel 1c: mask validity mm[k] -----------------------------------------
__global__ void k_prep_mm(const float* __restrict__ mask, float* __restrict__ mmv) {
  int k = blockIdx.x * 256 + threadIdx.x;
  if (k >= L) return;
  int ky = k >> 6, kx = k & 63;
  float s = 0.f;
  for (int i = 0; i < 3; ++i)
    for (int j = 0; j < 3; ++j) {
      int yy = ky + i - 1, xx = kx + j - 1;
      if (yy >= 0 && yy < 64 && xx >= 0 && xx < 64) s += mask[yy * 64 + xx];
    }
  mmv[k] = (s == 0.f) ? 1.f : 0.f;
}

// ---------------- kernel 2: scores GEMM  S[k,q] = sum_d WN[k,d]*FP[q,d], f16 out ---------
__global__ __launch_bounds__(256) void k_gemm_scores(
    const f16* __restrict__ WN, const f16* __restrict__ FP, f16* __restrict__ S) {
  __shared__ f16 As[128 * 32];
  __shared__ f16 Bs[128 * 32];
  int qt = blockIdx.x, kt = blockIdx.y, batch = blockIdx.z;
  int tid = threadIdx.x, wid = tid >> 6, lane = tid & 63;
  int wr = wid >> 1, wc = wid & 1;
  const f16* Abase = WN + ((size_t)batch * L + kt * 128) * KD;
  const f16* Bbase = FP + ((size_t)batch * L + qt * 128) * KD;
  f32x4 acc[4][4] = {};
  int srow = lane >> 2;          // 0..15
  int scol = (lane & 3) * 8;     // f16 offset within 32
  for (int kk = 0; kk < KD; kk += 32) {
    __syncthreads();
    {
      int r0 = wid * 32 + srow;
      gl_lds16(Abase + (size_t)r0 * KD + kk + scol, As + r0 * 32 + scol);
      gl_lds16(Abase + (size_t)(r0 + 16) * KD + kk + scol, As + (r0 + 16) * 32 + scol);
      gl_lds16(Bbase + (size_t)r0 * KD + kk + scol, Bs + r0 * 32 + scol);
      gl_lds16(Bbase + (size_t)(r0 + 16) * KD + kk + scol, Bs + (r0 + 16) * 32 + scol);
    }
    __syncthreads();
    f16x8 af[4], bf[4];
    int kb = (lane >> 4) * 8;
    int rA = wr * 64 + (lane & 15);
    int rB = wc * 64 + (lane & 15);
#pragma unroll
    for (int m = 0; m < 4; ++m) af[m] = *(const f16x8*)(As + (rA + m * 16) * 32 + kb);
#pragma unroll
    for (int n = 0; n < 4; ++n) bf[n] = *(const f16x8*)(Bs + (rB + n * 16) * 32 + kb);
#pragma unroll
    for (int m = 0; m < 4; ++m)
#pragma unroll
      for (int n = 0; n < 4; ++n)
        acc[m][n] = __builtin_amdgcn_mfma_f32_16x16x32_f16(af[m], bf[n], acc[m][n], 0, 0, 0);
  }
  f16* Srow = S + (size_t)batch * L * L;
  int kbase = kt * 128 + wr * 64 + (lane >> 4) * 4;
  int qbase = qt * 128 + wc * 64 + (lane & 15);
#pragma unroll
  for (int m = 0; m < 4; ++m)
#pragma unroll
    for (int r = 0; r < 4; ++r) {
      f16* dst = Srow + (size_t)(kbase + m * 16 + r) * L + qbase;
#pragma unroll
      for (int n = 0; n < 4; ++n) dst[n * 16] = (f16)acc[m][n][r];
    }
}

// ---------------- kernel 2b: full fuse, S (f16) -> T3 = 10*fused (f32) -------------------
// T3[k][j] = 10 * sum_u valid_u * T1[r_u][c_u(j)], T1 computed on the fly (3 taps each)
__global__ __launch_bounds__(256) void k_fuse(
    const f16* __restrict__ S, float* __restrict__ T3) {
  int k = blockIdx.x;
  int batch = blockIdx.z;
  int j0 = (blockIdx.y * 256 + threadIdx.x) * 8;
  const f16* Sb = S + (size_t)batch * L * L;
  float* dst = T3 + (size_t)batch * L * L + (size_t)k * L + j0;
  if (j0 < 64 || j0 >= 4032) {   // edge column bands: scalar path
#pragma unroll
    for (int e = 0; e < 8; ++e) dst[e] = 10.f * fuse9(Sb, k, j0 + e);
    return;
  }
  int cK = sigma_(k);
  float acc[8] = {0.f, 0.f, 0.f, 0.f, 0.f, 0.f, 0.f, 0.f};
#pragma unroll
  for (int u = -1; u <= 1; ++u) {
    int a = cK + u;
    if ((unsigned)a >= L) continue;
    int r = sigma_(a);
    int c = j0 + 64 * u;         // interior column mapping
    float t[8];
    {
      f16x8 Bv = *(const f16x8*)(Sb + (size_t)r * L + c);
#pragma unroll
      for (int e = 0; e < 8; ++e) t[e] = (float)Bv[e];
    }
    if (r > 0) {
      const f16* Rm = Sb + (size_t)(r - 1) * L + c;
      f16x8 A1 = *(const f16x8*)Rm;
      t[0] += (c > 0) ? (float)Rm[-1] : 0.f;
#pragma unroll
      for (int e = 1; e < 8; ++e) t[e] += (float)A1[e - 1];
    }
    if (r < L - 1) {
      const f16* Rp = Sb + (size_t)(r + 1) * L + c;
      f16x8 C0 = *(const f16x8*)Rp;
#pragma unroll
      for (int e = 0; e < 7; ++e) t[e] += (float)C0[e + 1];
      t[7] += (c + 8 < L) ? (float)Rp[8] : 0.f;
    }
#pragma unroll
    for (int e = 0; e < 8; ++e) acc[e] += t[e];
  }
#pragma unroll
  for (int e = 0; e < 8; ++e) acc[e] *= 10.f;
  *(f32x4*)dst = *(f32x4*)&acc[0];
  *(f32x4*)(dst + 4) = *(f32x4*)&acc[4];
}

// ---------------- kernel 3: online softmax partial stats over k chunks -------------------
__global__ __launch_bounds__(256) void k_softmax_stats(
    const float* __restrict__ T3, const float* __restrict__ mmv,
    float* __restrict__ pm, float* __restrict__ pl) {
  int q = blockIdx.x * 256 + threadIdx.x;
  int kc = blockIdx.y, batch = blockIdx.z;
  const float* Tb = T3 + (size_t)batch * L * L;
  float m = -3.0e38f, l = 0.f;
  int k0 = kc * 64;
#pragma unroll 4
  for (int kk = 0; kk < 64; ++kk) {
    int k = k0 + kk;
    float logit = (mmv[k] != 0.f) ? Tb[(size_t)k * L + q] : 0.f;
    float nm = fmaxf(m, logit);
    l = l * __expf(m - nm) + __expf(logit - nm);
    m = nm;
  }
  int qi = batch * L + q;
  pm[kc * (BB * L) + qi] = m;
  pl[kc * (BB * L) + qi] = l;
}

// ---------------- kernel 3b: combine partials -------------------------------------------
__global__ void k_softmax_reduce(const float* __restrict__ pm, const float* __restrict__ pl,
                                 float* __restrict__ Mq, float* __restrict__ Lq) {
  int qi = blockIdx.x * 256 + threadIdx.x;
  if (qi >= BB * L) return;
  float M = -3.0e38f;
#pragma unroll 8
  for (int i = 0; i < 64; ++i) M = fmaxf(M, pm[i * (BB * L) + qi]);
  float Ls = 0.f;
#pragma unroll 8
  for (int i = 0; i < 64; ++i) Ls += pl[i * (BB * L) + qi] * __expf(pm[i * (BB * L) + qi] - M);
  Mq[qi] = M;
  Lq[qi] = Ls;
}

// ---------------- kernel 4: write attn (f16, [b][k][q]) ---------------------------------
__global__ __launch_bounds__(256) void k_attn(
    const float* __restrict__ T3, const float* __restrict__ mmv,
    const float* __restrict__ Mq, const float* __restrict__ Lq,
    f16* __restrict__ attn) {
  int q = blockIdx.x * 256 + threadIdx.x;
  int kc = blockIdx.y, batch = blockIdx.z;
  const float* Tb = T3 + (size_t)batch * L * L;
  f16* An = attn + (size_t)batch * L * L;
  int qi = batch * L + q;
  float M = Mq[qi];
  float inv = 1.f / Lq[qi];
  int k0 = kc * 64;
#pragma unroll 4
  for (int kk = 0; kk < 64; ++kk) {
    int k = k0 + kk;
    float v = 0.f;
    if (mmv[k] != 0.f) v = __expf(Tb[(size_t)k * L + q] - M) * inv;
    An[(size_t)k * L + q] = (f16)v;
  }
}

// ---------------- kernel 5: aggregation, K-split partials --------------------------------
// part[ks][batch][c][p] = sum_{k in chunk} sum_tap bm[tap][batch][c][k] * attn[k][p+dlt]
__global__ __launch_bounds__(512) void k_agg(
    const f16* __restrict__ attn, const f16* __restrict__ bm, float* __restrict__ part) {
  __shared__ f16 Asm[512 * 32];   // [R=tap*128+c][32kk], chunk-swizzled: phys = log ^ ((R>>1)&3)
  __shared__ f16 Bt[136 * 40];    // [pp][kk], kk-chunk swizzled: phys = log ^ ((pp>>3)&3)
  int pt = blockIdx.x, ks = blockIdx.y, batch = blockIdx.z;
  int p0 = pt * 64;
  int tid = threadIdx.x, wid = tid >> 6, lane = tid & 63;
  int wr = wid >> 1, wc = wid & 1;
  const f16* attnB = attn + (size_t)batch * L * L;
  f32x4 acc[2][2] = {};
  int kend = ks * 1024 + 1024;
  for (int k0 = ks * 1024; k0 < kend; k0 += 32) {
    __syncthreads();
    // A staging via global_load_lds, source-XOR-swizzled (read side 2-way = free)
#pragma unroll
    for (int i = 0; i < 4; ++i) {
      int R = wid * 64 + i * 16 + (lane >> 2);
      int tap = R >> 7, c = R & 127;
      int chl = (lane & 3) ^ ((R >> 1) & 3);
      const f16* g = bm + (((size_t)(tap * 2 + batch) * CC + c) * L) + k0 + chl * 8;
      gl_lds16(g, Asm + R * 32 + (lane & 3) * 8);
    }
    // B staging: transpose attn[k0+kk][p0+pp] -> Bt[pp][kk], 544 tasks
    for (int tau = tid; tau < 544; tau += 512) {
      int kk = tau / 17, ch = tau - kk * 17;
      int pbase = p0 + ch * 8;
      const f16* src = attnB + (size_t)(k0 + kk) * L + pbase;
      f16 v[8];
      if (pbase + 7 < L) {
        f16x8 vv = *(const f16x8*)src;
#pragma unroll
        for (int e = 0; e < 8; ++e) v[e] = vv[e];
      } else {
#pragma unroll
        for (int e = 0; e < 8; ++e) v[e] = (pbase + e < L) ? src[e] : (f16)0.f;
      }
#pragma unroll
      for (int e = 0; e < 8; ++e) {
        int pp = ch * 8 + e;
        Bt[pp * 40 + (((kk >> 3) ^ ((pp >> 3) & 3)) * 8) + (kk & 7)] = v[e];
      }
    }
    __syncthreads();
#pragma unroll
    for (int tap = 0; tap < 4; ++tap) {
      int dlt = (tap >> 1) * 64 + (tap & 1);
      f16x8 af[2], bf[2];
#pragma unroll
      for (int m = 0; m < 2; ++m) {
        int R = tap * 128 + wr * 32 + m * 16 + (lane & 15);
        int ph = (lane >> 4) ^ ((R >> 1) & 3);
        af[m] = *(const f16x8*)(Asm + R * 32 + ph * 8);
      }
#pragma unroll
      for (int n = 0; n < 2; ++n) {
        int pp = wc * 32 + n * 16 + (lane & 15) + dlt;
        int ph = (lane >> 4) ^ ((pp >> 3) & 3);
        bf[n] = *(const f16x8*)(Bt + pp * 40 + ph * 8);
      }
#pragma unroll
      for (int m = 0; m < 2; ++m)
#pragma unroll
        for (int n = 0; n < 2; ++n)
          acc[m][n] = __builtin_amdgcn_mfma_f32_16x16x32_f16(af[m], bf[n], acc[m][n], 0, 0, 0);
    }
  }
  int cb = wr * 32 + (lane >> 4) * 4;
  int pb = p0 + wc * 32 + (lane & 15);
#pragma unroll
  for (int m = 0; m < 2; ++m)
#pragma unroll
    for (int n = 0; n < 2; ++n)
#pragma unroll
      for (int r = 0; r < 4; ++r) {
        int c = cb + m * 16 + r;
        int p = pb + n * 16;
        part[(((size_t)ks * 2 + batch) * CC + c) * L + p] = acc[m][n][r];
      }
}

// ---------------- kernel 5b: sum K-split partials, scale, border mask --------------------
__global__ void k_agg_reduce(const float* __restrict__ part, float* __restrict__ out) {
  int idx = blockIdx.x * 256 + threadIdx.x;   // 2*128*4096
  int p = idx & (L - 1);
  float s = 0.f;
#pragma unroll
  for (int ks = 0; ks < 4; ++ks) s += part[(size_t)ks * (2 * CC * L) + idx];
  int u = p >> 6, v = p & 63;
  out[idx] = (u < 63 && v < 63) ? s * 0.25f : 0.f;
}

extern "C" void kernel_launch(void* const* d_in, const int* in_sizes, int n_in,
                              void* d_out, int out_size, void* d_ws, size_t ws_size,
                              hipStream_t stream) {
  const float* f = (const float*)d_in[0];
  const float* b = (const float*)d_in[1];
  const float* mask = (const float*)d_in[2];
  float* out = (float*)d_out;
  char* ws = (char*)d_ws;

  // Lifetimes: WN/FP(prep->gemm) -> T3 overwrites them; S(gemm->fuse) -> attn overwrites.
  f16* WN    = (f16*)(ws + 0);             // 18,874,368
  f16* FP    = (f16*)(ws + 18874368);      // 18,874,368
  float* T3  = (float*)(ws + 0);           // 134,217,728 (after gemm; over WN/FP)
  f16* S     = (f16*)(ws + 134217728);     // 67,108,864
  f16* attn  = (f16*)(ws + 134217728);     // aliases S (dead after k_fuse)
  f16* bm    = (f16*)(ws + 201326592);     // 8,388,608
  float* part= (float*)(ws + 209715200);   // 16,777,216
  float* pm  = (float*)(ws + 226492416);   // 2,097,152
  float* pl  = (float*)(ws + 228589568);   // 2,097,152
  float* mmv = (float*)(ws + 230686720);   // 16,384
  float* Mq  = (float*)(ws + 230703104);   // 32,768
  float* Lq  = (float*)(ws + 230735872);   // 32,768

  k_prep_patches<<<dim3(2048), dim3(256), 0, stream>>>(f, b, WN, FP);
  k_prep_bm<<<dim3(16384), dim3(256), 0, stream>>>(b, bm);
  k_prep_mm<<<dim3(16), dim3(256), 0, stream>>>(mask, mmv);
  k_gemm_scores<<<dim3(32, 32, 2), dim3(256), 0, stream>>>(WN, FP, S);
  k_fuse<<<dim3(4096, 2, 2), dim3(256), 0, stream>>>(S, T3);
  k_softmax_stats<<<dim3(16, 64, 2), dim3(256), 0, stream>>>(T3, mmv, pm, pl);
  k_softmax_reduce<<<dim3(32), dim3(256), 0, stream>>>(pm, pl, Mq, Lq);
  k_attn<<<dim3(16, 64, 2), dim3(256), 0, stream>>>(T3, mmv, Mq, Lq, attn);
  k_agg<<<dim3(64, 4, 2), dim3(512), 0, stream>>>(attn, bm, part);
  k_agg_reduce<<<dim3(4096), dim3(256), 0, stream>>>(part, out);
}